// Round 3
// baseline (278.661 us; speedup 1.0000x reference)
//
#include <hip/hip_runtime.h>
#include <math.h>

#define EMBS_DIM 300
#define TPB 1024
#define NBLOCKS 512

// Fused kernel: each block (1) redundantly computes the 300-element noise
// vector into LDS via a ballot-based block prefix scan over the samples
// (acceptance prob ~11.5%, so ~3 chunks of 1024 samples; reads are L2-hot
// across blocks), then (2) grid-strides the float4 broadcast-add.
__global__ __launch_bounds__(TPB) void fused_noise_add_kernel(
    const float4* __restrict__ embs, const float* __restrict__ sgn,
    const float* __restrict__ u, int n, float4* __restrict__ out,
    int total4, float scale, float A)
{
    __shared__ int s_wave_tot[TPB / 64];
    __shared__ __align__(16) float s_noise[EMBS_DIM + 4];  // pad to float4

    const int tid  = threadIdx.x;
    const int lane = tid & 63;
    const int wave = tid >> 6;
    const int nwaves = TPB / 64;

    // Zero-init noise (covers the short-fill case).
    if (tid < EMBS_DIM + 4) s_noise[tid] = 0.0f;
    __syncthreads();

    // ---- Phase 1: block-local scan producing first 300 accepted values ----
    int base = 0;  // accepted so far; uniform across block
    for (int i0 = 0; i0 < n; i0 += TPB) {
        const int i = i0 + tid;
        float r = 0.0f;
        int m = 0;
        if (i < n) {
            const float s  = sgn[i];
            const float sg = (s > 0.0f) ? 1.0f : ((s < 0.0f) ? -1.0f : 0.0f);
            r = (-scale * sg) * logf(u[i]);
            m = (r >= -A && r <= A) ? 1 : 0;
        }
        const unsigned long long bal = __ballot(m);
        if (lane == 0) s_wave_tot[wave] = __popcll(bal);
        __syncthreads();
        int woff = 0, tot = 0;
        #pragma unroll
        for (int w = 0; w < nwaves; ++w) {
            const int t = s_wave_tot[w];
            if (w < wave) woff += t;
            tot += t;
        }
        const int lpre = __popcll(bal & ((1ull << lane) - 1ull));
        const int pos  = base + woff + lpre;
        if (m && pos < EMBS_DIM) s_noise[pos] = r;
        base += tot;
        __syncthreads();  // s_wave_tot reuse + s_noise visibility
        if (base >= EMBS_DIM) break;
    }
    __syncthreads();  // ensure s_noise complete before the add phase

    // ---- Phase 2: grid-stride broadcast add, float4 ----
    const float4* noise4 = (const float4*)s_noise;       // 75 entries
    const int stride = gridDim.x * TPB;
    // j = i % 75 maintained incrementally: stride % 75 precomputed.
    const int jstep = stride % 75;
    int i = blockIdx.x * TPB + tid;
    int j = i % 75;
    for (; i < total4; i += stride) {
        const float4 e  = embs[i];
        const float4 nv = noise4[j];   // LDS read, conflict-light
        float4 o;
        o.x = e.x + nv.x;
        o.y = e.y + nv.y;
        o.z = e.z + nv.z;
        o.w = e.w + nv.w;
        out[i] = o;
        j += jstep;
        if (j >= 75) j -= 75;
    }
}

extern "C" void kernel_launch(void* const* d_in, const int* in_sizes, int n_in,
                              void* d_out, int out_size, void* d_ws, size_t ws_size,
                              hipStream_t stream)
{
    const float* embs = (const float*)d_in[0];
    const float* sgn  = (const float*)d_in[1];
    const float* u    = (const float*)d_in[2];
    float* out = (float*)d_out;

    const int n = in_sizes[1];  // N_SAMPLES = 1,000,000

    // Match Python: _SCALE/_A computed in float64, cast to float32.
    const double scaled = 2.0 * 0.005 * sqrt(300.0) / 1.0;
    const double Ad     = -scaled * log(1.0 - 2.0 * 1.0 / sqrt(300.0));
    const float scale = (float)scaled;
    const float A     = (float)Ad;

    const int total4 = out_size / 4;  // 9,830,400

    fused_noise_add_kernel<<<NBLOCKS, TPB, 0, stream>>>(
        (const float4*)embs, sgn, u, n, (float4*)out, total4, scale, A);
}